// Round 5
// baseline (123.044 us; speedup 1.0000x reference)
//
#include <hip/hip_runtime.h>

#define N_SAMP 1024
#define XD     128
#define HID    256

// ---------------------------------------------------------------------------
// Workspace layout (float indices):
//   [0, 1024)            S       per-i sum of exp(T1[i,j]) over j
//   [1024]               T0sum   sum over i of T1[i,i]  (diagonal, sans b2)
//   [1025]               ticket counter (uint bits), last-block-done
//   [2048, 2048+256K)    xpbT    (x @ W1x + b1)^T   [HID][N]  (k-major)
//   [next 256K)          ypT     (y @ W1y)^T        [HID][N]  (k-major)
// S/T0sum/ticket zeroed by gemm_xy every launch (ws is poisoned 0xAA).
// ---------------------------------------------------------------------------

// Kernel 1: the two small GEMMs, writing TRANSPOSED outputs. Thread k owns
// hidden unit k for 4 consecutive rows -> in k-major layout those 4 results
// are contiguous: one float4 store per array. Also zeroes S/T0sum/ticket.
__global__ __launch_bounds__(256) void gemm_xy(
    const float* __restrict__ x, const float* __restrict__ y,
    const float* __restrict__ W1, const float* __restrict__ b1,
    float* __restrict__ xpbT, float* __restrict__ ypT,
    float* __restrict__ S, float* __restrict__ T0sum)
{
    const int k  = threadIdx.x;        // hidden unit 0..255
    const int r0 = blockIdx.x * 4;     // 4 rows per block

    // Zero accumulators (256 blocks x 4 = 1024 S entries; block 0: T0+ticket).
    if (threadIdx.x < 4) S[blockIdx.x * 4 + threadIdx.x] = 0.f;
    if (blockIdx.x == 0 && threadIdx.x == 4) T0sum[0] = 0.f;
    if (blockIdx.x == 0 && threadIdx.x == 5) ((unsigned*)T0sum)[1] = 0u;

    float ax0 = 0.f, ax1 = 0.f, ax2 = 0.f, ax3 = 0.f;
    float ay0 = 0.f, ay1 = 0.f, ay2 = 0.f, ay3 = 0.f;

    #pragma unroll 4
    for (int d = 0; d < XD; ++d) {
        const float wx = W1[d * HID + k];            // coalesced over k
        const float wy = W1[(XD + d) * HID + k];
        ax0 = fmaf(x[(r0 + 0) * XD + d], wx, ax0);   // uniform -> s_load
        ax1 = fmaf(x[(r0 + 1) * XD + d], wx, ax1);
        ax2 = fmaf(x[(r0 + 2) * XD + d], wx, ax2);
        ax3 = fmaf(x[(r0 + 3) * XD + d], wx, ax3);
        ay0 = fmaf(y[(r0 + 0) * XD + d], wy, ay0);
        ay1 = fmaf(y[(r0 + 1) * XD + d], wy, ay1);
        ay2 = fmaf(y[(r0 + 2) * XD + d], wy, ay2);
        ay3 = fmaf(y[(r0 + 3) * XD + d], wy, ay3);
    }

    const float bk = b1[k];
    float4 xs4 = make_float4(ax0 + bk, ax1 + bk, ax2 + bk, ax3 + bk);
    float4 ys4 = make_float4(ay0, ay1, ay2, ay3);
    *(float4*)&xpbT[k * N_SAMP + r0] = xs4;  // 16B-aligned (r0 % 4 == 0)
    *(float4*)&ypT [k * N_SAMP + r0] = ys4;
}

// Kernel 2 (the only other launch): pairwise relu-dot, row-sums of exp,
// diagonal, AND final reduction (last-block ticket).
//
// r4 post-mortem: per-kernel wins were eaten by launch count — so keep the
// all-LDS inner loop (16 accs/thread; 48 useful VALU per k vs 2 ds_read_b128
// with compile-time offsets; VALU 96 cy/k/SIMD vs LDS 96 cy/k/CU, balanced)
// but drop split-K: each block owns a full 64x64 tile, walking K=256 in TWO
// LDS passes of 64 KB (xs[128][64] + ys[128][64] = exactly the 64 KB static
// limit). Grid 16x16 = 256 blocks = 1/CU. No global loads in the k-loop:
// 1 wave/SIMD suffices (unroll-8 batches 16 ds_reads; compiler lgkmcnt
// pipelining covers ~120 cy LDS latency).
__global__ __launch_bounds__(256) void pair_fused(
    const float* __restrict__ ypT, const float* __restrict__ xpbT,
    const float* __restrict__ W2,
    float* __restrict__ S, float* __restrict__ T0s,
    const float* __restrict__ b2, float* __restrict__ out)
{
    __shared__ float xs[128][64];      // [kk][j] 32 KB
    __shared__ float ys[128][64];      // [kk][i] 32 KB

    const int tid = threadIdx.x;
    const int tj  = tid & 15;
    const int ti  = tid >> 4;
    const int jb  = blockIdx.x * 64;
    const int ib  = blockIdx.y * 64;
    const int j0  = jb + tj * 4;
    const int i0  = ib + ti * 4;

    float acc[4][4];
    #pragma unroll
    for (int a = 0; a < 4; ++a)
        #pragma unroll
        for (int b = 0; b < 4; ++b) acc[a][b] = 0.f;

    for (int pass = 0; pass < 2; ++pass) {
        const int kof = pass << 7;             // 0, 128
        if (pass) __syncthreads();             // all waves done with pass-0 LDS

        // Stage both panels: 2048 float4 each, 8 per thread per panel.
        // 16 consecutive lanes cover one 256 B row -> coalesced global reads,
        // contiguous 2-way-aliased (free) LDS writes.
        #pragma unroll
        for (int s = 0; s < 8; ++s) {
            const int f  = s * 256 + tid;
            const int kk = f >> 4;
            const int q  = (f & 15) * 4;
            *(float4*)&xs[kk][q] = *(const float4*)&xpbT[(kof + kk) * N_SAMP + jb + q];
            *(float4*)&ys[kk][q] = *(const float4*)&ypT [(kof + kk) * N_SAMP + ib + q];
        }
        __syncthreads();

        #pragma unroll 8
        for (int kk = 0; kk < 128; ++kk) {
            const float4 xv = *(const float4*)&xs[kk][tj * 4]; // 16 addrs, bcast+2way
            const float4 yv = *(const float4*)&ys[kk][ti * 4]; // 4 addrs, bcast
            const float  w  = W2[kof + kk];                    // uniform -> s_load
            const float xa[4] = {xv.x, xv.y, xv.z, xv.w};
            const float ya[4] = {yv.x, yv.y, yv.z, yv.w};
            #pragma unroll
            for (int a = 0; a < 4; ++a)
                #pragma unroll
                for (int b = 0; b < 4; ++b)
                    acc[a][b] = fmaf(fmaxf(ya[a] + xa[b], 0.f), w, acc[a][b]);
        }
    }

    // Row sums of exp over this thread's 4 j's, then across the 16 tj lanes
    // (contiguous within a wave), then one atomic per i per block.
    // |acc| ~ O(1): exp without max-shift is safe in f32.
    #pragma unroll
    for (int a = 0; a < 4; ++a) {
        float e = __expf(acc[a][0]) + __expf(acc[a][1])
                + __expf(acc[a][2]) + __expf(acc[a][3]);
        #pragma unroll
        for (int off = 8; off; off >>= 1) e += __shfl_xor(e, off, 16);
        if (tj == 0) atomicAdd(&S[i0 + a], e);
    }

    // Diagonal (T0): 64x64 tiles -> diag blocks are blockIdx.x == blockIdx.y;
    // there, i0+a == j0+b  <=>  ti == tj && a == b.
    if (blockIdx.x == blockIdx.y) {
        float dv = 0.f;
        if (ti == tj)
            dv = acc[0][0] + acc[1][1] + acc[2][2] + acc[3][3];
        #pragma unroll
        for (int off = 32; off; off >>= 1) dv += __shfl_xor(dv, off, 64);
        if ((tid & 63) == 0) atomicAdd(&T0s[0], dv);
    }

    // ---- last-block-done finalize (replaces a 3rd kernel launch) ----
    // No spin loops: deadlock-free. Ticket counter re-zeroed by gemm_xy
    // every graph replay. All S/T0 traffic is device-scope atomics, so the
    // coherence point holds the totals; read back via atomicAdd(p, 0.f).
    int* lastflag = (int*)&ys[0][0];           // reuse LDS (over-limit otherwise)
    __threadfence();                           // my atomics visible device-wide
    __syncthreads();                           // all lanes' fences done
    if (tid == 0)
        *lastflag = (atomicAdd((unsigned*)&T0s[1], 1u) == 255u);
    __syncthreads();
    if (!*lastflag) return;

    float* red = &xs[0][0];                    // reuse LDS for reduction
    float ls = 0.f;
    for (int i = tid; i < N_SAMP; i += 256)
        ls += logf(atomicAdd(&S[i], 0.f));
    #pragma unroll
    for (int off = 32; off; off >>= 1) ls += __shfl_xor(ls, off, 64);
    if ((tid & 63) == 0) red[tid >> 6] = ls;
    __syncthreads();

    if (tid == 0) {
        const float t0       = atomicAdd(&T0s[0], 0.f);
        const float lse_sum  = red[0] + red[1] + red[2] + red[3];
        const float t0_mean  = t0 / (float)N_SAMP + b2[0];
        const float lse_mean = lse_sum / (float)N_SAMP + b2[0]
                             - logf((float)N_SAMP);
        out[0] = t0_mean - lse_mean;
    }
}

extern "C" void kernel_launch(void* const* d_in, const int* in_sizes, int n_in,
                              void* d_out, int out_size, void* d_ws, size_t ws_size,
                              hipStream_t stream)
{
    const float* x  = (const float*)d_in[0];
    const float* y  = (const float*)d_in[1];
    const float* W1 = (const float*)d_in[2];
    const float* b1 = (const float*)d_in[3];
    const float* W2 = (const float*)d_in[4];
    const float* b2 = (const float*)d_in[5];

    float* ws   = (float*)d_ws;
    float* S    = ws;                          // 1024 floats
    float* T0s  = ws + 1024;                   // [0]=T0sum, [1]=ticket
    float* xpbT = ws + 2048;                   // [HID][N]
    float* ypT  = ws + 2048 + HID * N_SAMP;    // [HID][N]

    gemm_xy   <<<dim3(N_SAMP / 4), dim3(256), 0, stream>>>(x, y, W1, b1,
                                                           xpbT, ypT, S, T0s);
    pair_fused<<<dim3(16, 16),     dim3(256), 0, stream>>>(ypT, xpbT, W2,
                                                           S, T0s, b2,
                                                           (float*)d_out);
}

// Round 6
// 120.941 us; speedup vs baseline: 1.0174x; 1.0174x over previous
//
#include <hip/hip_runtime.h>

#define N_SAMP 1024
#define XD     128
#define HID    256

// ---------------------------------------------------------------------------
// Workspace layout (float indices):
//   [0, 1024)            S       per-i sum of exp(T1[i,j]) over j
//   [1024]               T0sum   sum over i of T1[i,i]  (diagonal, sans b2)
//   [1025]               ticket counter (uint bits), last-block-done
//   [2048, 2048+256K)    xpbT    (x @ W1x + b1)^T   [HID][N]  (k-major)
//   [next 256K)          ypT     (y @ W1y)^T        [HID][N]  (k-major)
// S/T0sum/ticket zeroed by gemm_xy every launch (ws is poisoned 0xAA).
// ---------------------------------------------------------------------------

// Kernel 1: the two small GEMMs, writing TRANSPOSED outputs. Thread k owns
// hidden unit k for 4 consecutive rows -> in k-major layout those 4 results
// are contiguous: one float4 store per array. Also zeroes S/T0sum/ticket.
__global__ __launch_bounds__(256) void gemm_xy(
    const float* __restrict__ x, const float* __restrict__ y,
    const float* __restrict__ W1, const float* __restrict__ b1,
    float* __restrict__ xpbT, float* __restrict__ ypT,
    float* __restrict__ S, float* __restrict__ T0sum)
{
    const int k  = threadIdx.x;        // hidden unit 0..255
    const int r0 = blockIdx.x * 4;     // 4 rows per block

    // Zero accumulators (256 blocks x 4 = 1024 S entries; block 0: T0+ticket).
    if (threadIdx.x < 4) S[blockIdx.x * 4 + threadIdx.x] = 0.f;
    if (blockIdx.x == 0 && threadIdx.x == 4) T0sum[0] = 0.f;
    if (blockIdx.x == 0 && threadIdx.x == 5) ((unsigned*)T0sum)[1] = 0u;

    float ax0 = 0.f, ax1 = 0.f, ax2 = 0.f, ax3 = 0.f;
    float ay0 = 0.f, ay1 = 0.f, ay2 = 0.f, ay3 = 0.f;

    #pragma unroll 4
    for (int d = 0; d < XD; ++d) {
        const float wx = W1[d * HID + k];            // coalesced over k
        const float wy = W1[(XD + d) * HID + k];
        ax0 = fmaf(x[(r0 + 0) * XD + d], wx, ax0);   // uniform -> s_load
        ax1 = fmaf(x[(r0 + 1) * XD + d], wx, ax1);
        ax2 = fmaf(x[(r0 + 2) * XD + d], wx, ax2);
        ax3 = fmaf(x[(r0 + 3) * XD + d], wx, ax3);
        ay0 = fmaf(y[(r0 + 0) * XD + d], wy, ay0);
        ay1 = fmaf(y[(r0 + 1) * XD + d], wy, ay1);
        ay2 = fmaf(y[(r0 + 2) * XD + d], wy, ay2);
        ay3 = fmaf(y[(r0 + 3) * XD + d], wy, ay3);
    }

    const float bk = b1[k];
    float4 xs4 = make_float4(ax0 + bk, ax1 + bk, ax2 + bk, ax3 + bk);
    float4 ys4 = make_float4(ay0, ay1, ay2, ay3);
    *(float4*)&xpbT[k * N_SAMP + r0] = xs4;  // 16B-aligned (r0 % 4 == 0)
    *(float4*)&ypT [k * N_SAMP + r0] = ys4;
}

// Kernel 2: pairwise relu-dot, row-sums of exp, diagonal, + ticket finalize.
//
// r5 post-mortem: W2[k] uniform load -> s_load; SMEM shares lgkmcnt with
// ds_read AND returns out-of-order, forcing lgkmcnt(0) drains that killed
// all LDS pipelining (VALUBusy 31%, ~470 cy/k vs 96 cy floor). Fix: NO SMEM
// in the k-loop — W2 lives in LDS (1 KB, staged once), read per 8-k chunk
// as two broadcast ds_read_b128 (same-address = conflict-free; DS is
// in-order so counted lgkmcnt(N) pipelining works). K walked in 4 passes
// of 64 (xs[64][64]+ys[64][64]+wlds = 33 KB); chunk loop kept runtime
// (unroll 2) so the pass body stays well under the 32 KB I-cache.
__global__ __launch_bounds__(256) void pair_fused(
    const float* __restrict__ ypT, const float* __restrict__ xpbT,
    const float* __restrict__ W2,
    float* __restrict__ S, float* __restrict__ T0s,
    const float* __restrict__ b2, float* __restrict__ out)
{
    __shared__ float xs[64][64];       // [kk][j] 16 KB
    __shared__ float ys[64][64];       // [kk][i] 16 KB
    __shared__ float wlds[HID];        // 1 KB

    const int tid = threadIdx.x;
    const int tj  = tid & 15;
    const int ti  = tid >> 4;
    const int jb  = blockIdx.x * 64;
    const int ib  = blockIdx.y * 64;
    const int j0  = jb + tj * 4;
    const int i0  = ib + ti * 4;
    const int tj4 = tj * 4, ti4 = ti * 4;

    // W2 -> LDS once (64 float4 by threads 0..63); first pass barrier covers.
    if (tid < 64) *(float4*)&wlds[tid * 4] = *(const float4*)&W2[tid * 4];

    float acc[4][4];
    #pragma unroll
    for (int a = 0; a < 4; ++a)
        #pragma unroll
        for (int b = 0; b < 4; ++b) acc[a][b] = 0.f;

    for (int pass = 0; pass < 4; ++pass) {
        const int kof = pass << 6;             // 0,64,128,192
        if (pass) __syncthreads();             // LDS free before restage

        // Stage both panels: 1024 float4 each, 4 per thread per panel.
        // 16 consecutive lanes cover one 256 B row -> coalesced global
        // reads, contiguous (2-way, free) LDS writes.
        #pragma unroll
        for (int s = 0; s < 4; ++s) {
            const int f  = s * 256 + tid;
            const int kk = f >> 4;
            const int q  = (f & 15) * 4;
            *(float4*)&xs[kk][q] = *(const float4*)&xpbT[(kof + kk) * N_SAMP + jb + q];
            *(float4*)&ys[kk][q] = *(const float4*)&ypT [(kof + kk) * N_SAMP + ib + q];
        }
        __syncthreads();

        // 8 chunks of 8 k. Per chunk per wave: 2 b128 (w, broadcast) +
        // 16 b128 (x,y) + 384 VALU — pure-DS lgkmcnt, pipelineable.
        #pragma unroll 2
        for (int c = 0; c < 8; ++c) {
            const int kb = c * 8;
            const float4 wa = *(const float4*)&wlds[kof + kb];
            const float4 wb = *(const float4*)&wlds[kof + kb + 4];
            const float wv[8] = {wa.x, wa.y, wa.z, wa.w,
                                 wb.x, wb.y, wb.z, wb.w};
            #pragma unroll
            for (int u = 0; u < 8; ++u) {
                const int kk = kb + u;
                const float4 xv = *(const float4*)&xs[kk][tj4];
                const float4 yv = *(const float4*)&ys[kk][ti4];
                const float xa[4] = {xv.x, xv.y, xv.z, xv.w};
                const float ya[4] = {yv.x, yv.y, yv.z, yv.w};
                #pragma unroll
                for (int a = 0; a < 4; ++a)
                    #pragma unroll
                    for (int b = 0; b < 4; ++b)
                        acc[a][b] = fmaf(fmaxf(ya[a] + xa[b], 0.f),
                                         wv[u], acc[a][b]);
            }
        }
    }

    // Row sums of exp over this thread's 4 j's, then across the 16 tj lanes
    // (contiguous within a wave), then one atomic per i per block.
    // |acc| ~ O(1): exp without max-shift is safe in f32.
    #pragma unroll
    for (int a = 0; a < 4; ++a) {
        float e = __expf(acc[a][0]) + __expf(acc[a][1])
                + __expf(acc[a][2]) + __expf(acc[a][3]);
        #pragma unroll
        for (int off = 8; off; off >>= 1) e += __shfl_xor(e, off, 16);
        if (tj == 0) atomicAdd(&S[i0 + a], e);
    }

    // Diagonal (T0): 64x64 tiles -> diag blocks are blockIdx.x == blockIdx.y;
    // there, i0+a == j0+b  <=>  ti == tj && a == b.
    if (blockIdx.x == blockIdx.y) {
        float dv = 0.f;
        if (ti == tj)
            dv = acc[0][0] + acc[1][1] + acc[2][2] + acc[3][3];
        #pragma unroll
        for (int off = 32; off; off >>= 1) dv += __shfl_xor(dv, off, 64);
        if ((tid & 63) == 0) atomicAdd(&T0s[0], dv);
    }

    // ---- last-block-done finalize (saves a 3rd kernel launch) ----
    // No spin loops: deadlock-free. Ticket re-zeroed by gemm_xy every
    // replay. All S/T0 traffic is device-scope atomics; read back via
    // atomicAdd(p, 0.f) so values come from the coherence point.
    int* lastflag = (int*)&ys[0][0];           // reuse LDS
    __threadfence();                           // my atomics visible device-wide
    __syncthreads();                           // all lanes' fences done
    if (tid == 0)
        *lastflag = (atomicAdd((unsigned*)&T0s[1], 1u) == 255u);
    __syncthreads();
    if (!*lastflag) return;

    float* red = &xs[0][0];                    // reuse LDS for reduction
    float ls = 0.f;
    for (int i = tid; i < N_SAMP; i += 256)
        ls += logf(atomicAdd(&S[i], 0.f));
    #pragma unroll
    for (int off = 32; off; off >>= 1) ls += __shfl_xor(ls, off, 64);
    if ((tid & 63) == 0) red[tid >> 6] = ls;
    __syncthreads();

    if (tid == 0) {
        const float t0       = atomicAdd(&T0s[0], 0.f);
        const float lse_sum  = red[0] + red[1] + red[2] + red[3];
        const float t0_mean  = t0 / (float)N_SAMP + b2[0];
        const float lse_mean = lse_sum / (float)N_SAMP + b2[0]
                             - logf((float)N_SAMP);
        out[0] = t0_mean - lse_mean;
    }
}

extern "C" void kernel_launch(void* const* d_in, const int* in_sizes, int n_in,
                              void* d_out, int out_size, void* d_ws, size_t ws_size,
                              hipStream_t stream)
{
    const float* x  = (const float*)d_in[0];
    const float* y  = (const float*)d_in[1];
    const float* W1 = (const float*)d_in[2];
    const float* b1 = (const float*)d_in[3];
    const float* W2 = (const float*)d_in[4];
    const float* b2 = (const float*)d_in[5];

    float* ws   = (float*)d_ws;
    float* S    = ws;                          // 1024 floats
    float* T0s  = ws + 1024;                   // [0]=T0sum, [1]=ticket
    float* xpbT = ws + 2048;                   // [HID][N]
    float* ypT  = ws + 2048 + HID * N_SAMP;    // [HID][N]

    gemm_xy   <<<dim3(N_SAMP / 4), dim3(256), 0, stream>>>(x, y, W1, b1,
                                                           xpbT, ypT, S, T0s);
    pair_fused<<<dim3(16, 16),     dim3(256), 0, stream>>>(ypT, xpbT, W2,
                                                           S, T0s, b2,
                                                           (float*)d_out);
}